// Round 1
// baseline (11113.214 us; speedup 1.0000x reference)
//
#include <hip/hip_runtime.h>

#define N_BOX 4096
#define NT    1024
#define KPT   (N_BOX / NT)   // 4 boxes per thread
#define NW    (NT / 64)      // 16 waves

__global__ __launch_bounds__(NT, 1) void soft_nms_kernel(
    const float* __restrict__ boxes,
    const float* __restrict__ scores,
    float* __restrict__ out)
{
    const int tid  = threadIdx.x;
    const int lane = tid & 63;
    const int wave = tid >> 6;

    __shared__ float s_val[NW];
    __shared__ int   s_idx[NW];
    __shared__ float s_box[5];

    // all per-box state lives in registers
    float bx1[KPT], by1[KPT], bx2[KPT], by2[KPT], barea[KPT];
    float cur[KPT], fin[KPT];

    #pragma unroll
    for (int k = 0; k < KPT; ++k) {
        const int i = tid * KPT + k;
        const float4 b = reinterpret_cast<const float4*>(boxes)[i];
        bx1[k] = b.x; by1[k] = b.y; bx2[k] = b.z; by2[k] = b.w;
        barea[k] = (b.z - b.x) * (b.w - b.y);
        cur[k] = scores[i];
        fin[k] = 0.0f;
    }

    const float neg_inv_sigma = -2.0f;  // -(1/SIGMA), SIGMA = 0.5

    for (int it = 0; it < N_BOX; ++it) {
        // ---- local argmax over this thread's 4 boxes (tie -> lowest idx) --
        float mv = cur[0];
        int   mi = tid * KPT;
        #pragma unroll
        for (int k = 1; k < KPT; ++k) {
            if (cur[k] > mv) { mv = cur[k]; mi = tid * KPT + k; }
        }
        // ---- 64-lane butterfly argmax reduce ----
        #pragma unroll
        for (int off = 1; off < 64; off <<= 1) {
            float ov = __shfl_xor(mv, off);
            int   oi = __shfl_xor(mi, off);
            if (ov > mv || (ov == mv && oi < mi)) { mv = ov; mi = oi; }
        }
        if (lane == 0) { s_val[wave] = mv; s_idx[wave] = mi; }
        __syncthreads();
        // ---- every thread redundantly reduces the 16 wave winners ----
        float bv = s_val[0];
        int   j  = s_idx[0];
        #pragma unroll
        for (int w = 1; w < NW; ++w) {
            float v = s_val[w]; int i2 = s_idx[w];
            if (v > bv || (v == bv && i2 < j)) { bv = v; j = i2; }
        }
        // ---- owner freezes score, publishes box from its registers ----
        if (tid == (j / KPT)) {
            const int k = j % KPT;
            fin[k] = cur[k];
            cur[k] = -__builtin_huge_valf();  // mark processed
            s_box[0] = bx1[k]; s_box[1] = by1[k];
            s_box[2] = bx2[k]; s_box[3] = by2[k];
            s_box[4] = barea[k];
        }
        __syncthreads();
        const float jx1 = s_box[0], jy1 = s_box[1];
        const float jx2 = s_box[2], jy2 = s_box[3];
        const float ja  = s_box[4];
        // ---- branch-free Gaussian decay of this thread's boxes ----
        #pragma unroll
        for (int k = 0; k < KPT; ++k) {
            float xx1 = fmaxf(jx1, bx1[k]);
            float yy1 = fmaxf(jy1, by1[k]);
            float xx2 = fminf(jx2, bx2[k]);
            float yy2 = fminf(jy2, by2[k]);
            float w = fmaxf(xx2 - xx1, 0.0f);
            float h = fmaxf(yy2 - yy1, 0.0f);
            float inter = w * h;
            float iou = inter / (ja + barea[k] - inter);
            float wt = __expf(iou * iou * neg_inv_sigma);
            cur[k] *= wt;   // -inf stays -inf for processed entries
        }
    }

    // ---- write scores + keep mask (0.0 / 1.0) ----
    #pragma unroll
    for (int k = 0; k < KPT; ++k) {
        const int i = tid * KPT + k;
        out[i] = fin[k];
        out[N_BOX + i] = (fin[k] > 0.05f) ? 1.0f : 0.0f;
    }
}

extern "C" void kernel_launch(void* const* d_in, const int* in_sizes, int n_in,
                              void* d_out, int out_size, void* d_ws, size_t ws_size,
                              hipStream_t stream) {
    const float* boxes  = (const float*)d_in[0];
    const float* scores = (const float*)d_in[1];
    float* out = (float*)d_out;
    soft_nms_kernel<<<1, NT, 0, stream>>>(boxes, scores, out);
}

// Round 2
// 6583.380 us; speedup vs baseline: 1.6881x; 1.6881x over previous
//
#include <hip/hip_runtime.h>

#define N_BOX 4096
#define NT    1024
#define KPT   4            // boxes per thread
#define NW    16           // waves
#define NEG_INF (-__builtin_huge_valf())

__global__ __launch_bounds__(NT, 1) void soft_nms_kernel(
    const float* __restrict__ boxes,
    const float* __restrict__ scores,
    float* __restrict__ out)
{
    const int tid  = threadIdx.x;
    const int lane = tid & 63;
    const int wave = tid >> 6;

    __shared__ unsigned s_key[N_BOX];     // 16 KB: (morton8 << 12) | orig_idx
    __shared__ float    s_wval[NW];       // per-wave max score
    __shared__ unsigned s_wpack[NW];      // per-wave argmax pack
    __shared__ float    s_box[5];         // selected box x1,y1,x2,y2,area

    // ---- build spatial sort keys: Morton cell of center | original index ----
    #pragma unroll
    for (int k = 0; k < KPT; ++k) {
        const int i = tid * KPT + k;
        const float4 b = reinterpret_cast<const float4*>(boxes)[i];
        const float cx = 0.5f * (b.x + b.z);
        const float cy = 0.5f * (b.y + b.w);
        int icx = (int)(cx * 0.016f); icx = icx < 0 ? 0 : (icx > 15 ? 15 : icx);
        int icy = (int)(cy * 0.016f); icy = icy < 0 ? 0 : (icy > 15 ? 15 : icy);
        unsigned m = 0;
        #pragma unroll
        for (int bb = 0; bb < 4; ++bb)
            m |= (((unsigned)(icx >> bb) & 1u) << (2*bb)) |
                 (((unsigned)(icy >> bb) & 1u) << (2*bb + 1));
        s_key[i] = (m << 12) | (unsigned)i;
    }
    __syncthreads();

    // ---- bitonic sort (ascending) of 4096 keys in LDS ----
    for (int kk = 2; kk <= N_BOX; kk <<= 1) {
        for (int j = kk >> 1; j > 0; j >>= 1) {
            #pragma unroll
            for (int t = 0; t < KPT; ++t) {
                const int e = tid + t * NT;
                const int p = e ^ j;
                if (p > e) {
                    const unsigned a = s_key[e], b = s_key[p];
                    const bool up = ((e & kk) == 0);
                    if ((a > b) == up) { s_key[e] = b; s_key[p] = a; }
                }
            }
            __syncthreads();
        }
    }

    // ---- gather boxes in sorted order; all state in registers ----
    float bx1[KPT], by1[KPT], bx2[KPT], by2[KPT], bar[KPT], cur[KPT], fin[KPT];
    unsigned pck[KPT];
    #pragma unroll
    for (int k = 0; k < KPT; ++k) {
        const int spos = tid * KPT + k;
        const int oi = (int)(s_key[spos] & 0xFFFu);
        const float4 b = reinterpret_cast<const float4*>(boxes)[oi];
        bx1[k] = b.x; by1[k] = b.y; bx2[k] = b.z; by2[k] = b.w;
        bar[k] = (b.z - b.x) * (b.w - b.y);
        cur[k] = scores[oi];
        fin[k] = 0.0f;
        pck[k] = ((unsigned)oi << 12) | (unsigned)spos;  // tie-break: min orig idx
    }

    // ---- wave bbox (kept in registers) + initial per-wave argmax ----
    float wbx1 = bx1[0], wby1 = by1[0], wbx2 = bx2[0], wby2 = by2[0];
    {
        float mv = cur[0]; unsigned mp = pck[0];
        #pragma unroll
        for (int k = 1; k < KPT; ++k) {
            wbx1 = fminf(wbx1, bx1[k]); wby1 = fminf(wby1, by1[k]);
            wbx2 = fmaxf(wbx2, bx2[k]); wby2 = fmaxf(wby2, by2[k]);
            if (cur[k] > mv || (cur[k] == mv && pck[k] < mp)) { mv = cur[k]; mp = pck[k]; }
        }
        #pragma unroll
        for (int off = 1; off < 64; off <<= 1) {
            wbx1 = fminf(wbx1, __shfl_xor(wbx1, off));
            wby1 = fminf(wby1, __shfl_xor(wby1, off));
            wbx2 = fmaxf(wbx2, __shfl_xor(wbx2, off));
            wby2 = fmaxf(wby2, __shfl_xor(wby2, off));
            const float ov = __shfl_xor(mv, off);
            const unsigned op = (unsigned)__shfl_xor((int)mp, off);
            if (ov > mv || (ov == mv && op < mp)) { mv = ov; mp = op; }
        }
        if (lane == 0) { s_wval[wave] = mv; s_wpack[wave] = mp; }
    }
    __syncthreads();

    // ---- main sequential loop: one selection per iteration ----
    for (int it = 0; it < N_BOX; ++it) {
        // global argmax: 16-lane butterfly over the 16 wave maxima
        const int r = lane & 15;
        float v = s_wval[r];
        unsigned p = s_wpack[r];
        #pragma unroll
        for (int off = 1; off < 16; off <<= 1) {
            const float ov = __shfl_xor(v, off);
            const unsigned op = (unsigned)__shfl_xor((int)p, off);
            if (ov > v || (ov == v && op < p)) { v = ov; p = op; }
        }
        const int spos = (int)(p & 0xFFFu);

        // owner freezes score and publishes box from registers
        if (tid == (spos >> 2)) {
            const int k = spos & 3;
            fin[k] = cur[k];
            cur[k] = NEG_INF;             // mark processed
            s_box[0] = bx1[k]; s_box[1] = by1[k];
            s_box[2] = bx2[k]; s_box[3] = by2[k];
            s_box[4] = bar[k];
        }
        __syncthreads();

        const float jx1 = s_box[0], jy1 = s_box[1];
        const float jx2 = s_box[2], jy2 = s_box[3], ja = s_box[4];
        // wave-level skip: no geometric overlap => all weights exactly 1.0
        const bool dirty = !(jx1 > wbx2 || jx2 < wbx1 || jy1 > wby2 || jy2 < wby1);
        if (dirty) {
            #pragma unroll
            for (int k = 0; k < KPT; ++k) {
                const float xx1 = fmaxf(jx1, bx1[k]);
                const float yy1 = fmaxf(jy1, by1[k]);
                const float xx2 = fminf(jx2, bx2[k]);
                const float yy2 = fminf(jy2, by2[k]);
                const float w = fmaxf(xx2 - xx1, 0.0f);
                const float h = fmaxf(yy2 - yy1, 0.0f);
                const float inter = w * h;
                const float iou = inter / (ja + bar[k] - inter);
                cur[k] *= __expf(iou * iou * -2.0f);   // -inf stays -inf
            }
            // recompute this wave's cached argmax
            float mv = cur[0]; unsigned mp = pck[0];
            #pragma unroll
            for (int k = 1; k < KPT; ++k)
                if (cur[k] > mv || (cur[k] == mv && pck[k] < mp)) { mv = cur[k]; mp = pck[k]; }
            #pragma unroll
            for (int off = 1; off < 64; off <<= 1) {
                const float ov = __shfl_xor(mv, off);
                const unsigned op = (unsigned)__shfl_xor((int)mp, off);
                if (ov > mv || (ov == mv && op < mp)) { mv = ov; mp = op; }
            }
            if (lane == 0) { s_wval[wave] = mv; s_wpack[wave] = mp; }
        }
        __syncthreads();
    }

    // ---- scatter outputs back to original order ----
    #pragma unroll
    for (int k = 0; k < KPT; ++k) {
        const int oi = (int)(pck[k] >> 12);
        out[oi] = fin[k];
        out[N_BOX + oi] = (fin[k] > 0.05f) ? 1.0f : 0.0f;
    }
}

extern "C" void kernel_launch(void* const* d_in, const int* in_sizes, int n_in,
                              void* d_out, int out_size, void* d_ws, size_t ws_size,
                              hipStream_t stream) {
    const float* boxes  = (const float*)d_in[0];
    const float* scores = (const float*)d_in[1];
    float* out = (float*)d_out;
    soft_nms_kernel<<<1, NT, 0, stream>>>(boxes, scores, out);
}

// Round 3
// 4241.833 us; speedup vs baseline: 2.6199x; 1.5520x over previous
//
#include <hip/hip_runtime.h>

#define N_BOX 4096
#define NT    1024
#define KPT   4            // boxes per thread
#define NW    16           // waves
#define MAXC  64           // max commits per round (= candidate count)
#define NEG_INF (-__builtin_huge_valf())

typedef unsigned long long u64;

__global__ __launch_bounds__(NT, 1) void soft_nms_kernel(
    const float* __restrict__ boxes,
    const float* __restrict__ scores,
    float* __restrict__ out)
{
    const int tid  = threadIdx.x;
    const int lane = tid & 63;
    const int wave = tid >> 6;

    __shared__ unsigned s_key[N_BOX];       // 16 KB, used for initial spatial sort
    __shared__ u64      s_wtop[NW][5];      // per-wave top-5 keys (desc)
    __shared__ float    s_wgeom[NW][4][5];  // geometry of per-wave top-4: x1,y1,x2,y2,area
    __shared__ int      s_cln[MAXC];        // commit t -> candidate slot (wave<<2|rank)
    __shared__ int      s_csp[MAXC];        // commit t -> sorted position of box
    __shared__ int      s_C;                // commits this round

    // ---- Morton keys of box centers (16x16 grid) | original index ----
    #pragma unroll
    for (int k = 0; k < KPT; ++k) {
        const int i = tid * KPT + k;
        const float4 b = reinterpret_cast<const float4*>(boxes)[i];
        const float cx = 0.5f * (b.x + b.z);
        const float cy = 0.5f * (b.y + b.w);
        int icx = (int)(cx * 0.016f); icx = icx < 0 ? 0 : (icx > 15 ? 15 : icx);
        int icy = (int)(cy * 0.016f); icy = icy < 0 ? 0 : (icy > 15 ? 15 : icy);
        unsigned m = 0;
        #pragma unroll
        for (int bb = 0; bb < 4; ++bb)
            m |= (((unsigned)(icx >> bb) & 1u) << (2*bb)) |
                 (((unsigned)(icy >> bb) & 1u) << (2*bb + 1));
        s_key[i] = (m << 12) | (unsigned)i;
    }
    __syncthreads();

    // ---- bitonic sort (ascending) of 4096 keys in LDS ----
    for (int kk = 2; kk <= N_BOX; kk <<= 1) {
        for (int j = kk >> 1; j > 0; j >>= 1) {
            #pragma unroll
            for (int t = 0; t < KPT; ++t) {
                const int e = tid + t * NT;
                const int p = e ^ j;
                if (p > e) {
                    const unsigned a = s_key[e], b = s_key[p];
                    const bool up = ((e & kk) == 0);
                    if ((a > b) == up) { s_key[e] = b; s_key[p] = a; }
                }
            }
            __syncthreads();
        }
    }

    // ---- gather boxes in spatially-sorted order; all state in registers ----
    float bx1[KPT], by1[KPT], bx2[KPT], by2[KPT], bar[KPT], cur[KPT], fin[KPT];
    unsigned klo[KPT];   // ((4095-oidx)<<13) | (spos+1)  -- low bits of sort key
    #pragma unroll
    for (int k = 0; k < KPT; ++k) {
        const int spos = tid * KPT + k;
        const int oi = (int)(s_key[spos] & 0xFFFu);
        const float4 b = reinterpret_cast<const float4*>(boxes)[oi];
        bx1[k] = b.x; by1[k] = b.y; bx2[k] = b.z; by2[k] = b.w;
        bar[k] = (b.z - b.x) * (b.w - b.y);
        cur[k] = scores[oi];
        fin[k] = 0.0f;
        klo[k] = ((unsigned)(4095 - oi) << 13) | (unsigned)(spos + 1);
    }

    // ---- wave bounding box (uniform within wave after butterfly) ----
    float wbx1 = bx1[0], wby1 = by1[0], wbx2 = bx2[0], wby2 = by2[0];
    #pragma unroll
    for (int k = 1; k < KPT; ++k) {
        wbx1 = fminf(wbx1, bx1[k]); wby1 = fminf(wby1, by1[k]);
        wbx2 = fmaxf(wbx2, bx2[k]); wby2 = fmaxf(wby2, by2[k]);
    }
    #pragma unroll
    for (int off = 1; off < 64; off <<= 1) {
        wbx1 = fminf(wbx1, __shfl_xor(wbx1, off));
        wby1 = fminf(wby1, __shfl_xor(wby1, off));
        wbx2 = fmaxf(wbx2, __shfl_xor(wbx2, off));
        wby2 = fmaxf(wby2, __shfl_xor(wby2, off));
    }

    // ---- batched selection rounds ----
    bool rebuild = true;
    int remaining = N_BOX;
    int guard = 0;
    while (remaining > 0 && ++guard <= N_BOX) {
        // (1) dirty waves rebuild cached top-5 (keys) + top-4 geometry
        if (rebuild) {
            u64 lk[KPT];
            #pragma unroll
            for (int k = 0; k < KPT; ++k)
                lk[k] = (cur[k] < 0.0f) ? 0ull
                        : (((u64)__float_as_uint(cur[k]) << 25) | (u64)klo[k]);
            #pragma unroll
            for (int p = 0; p < 5; ++p) {
                u64 m = lk[0];
                #pragma unroll
                for (int k = 1; k < KPT; ++k) m = lk[k] > m ? lk[k] : m;
                #pragma unroll
                for (int off = 1; off < 64; off <<= 1) {
                    const u64 o = __shfl_xor(m, off);
                    m = o > m ? o : m;
                }
                if (lane == 0) s_wtop[wave][p] = m;
                if (m != 0ull) {
                    #pragma unroll
                    for (int k = 0; k < KPT; ++k) {
                        if (lk[k] == m) {
                            lk[k] = 0ull;
                            if (p < 4) {
                                s_wgeom[wave][p][0] = bx1[k];
                                s_wgeom[wave][p][1] = by1[k];
                                s_wgeom[wave][p][2] = bx2[k];
                                s_wgeom[wave][p][3] = by2[k];
                                s_wgeom[wave][p][4] = bar[k];
                            }
                        }
                    }
                }
            }
        }
        __syncthreads();

        // (2) wave 0 simulates the exact sequential selection over 64 candidates
        if (wave == 0) {
            const int cw = lane >> 2, cr = lane & 3;
            u64 ck = s_wtop[cw][cr];
            const float cx1 = s_wgeom[cw][cr][0];
            const float cy1 = s_wgeom[cw][cr][1];
            const float cx2 = s_wgeom[cw][cr][2];
            const float cy2 = s_wgeom[cw][cr][3];
            const float car = s_wgeom[cw][cr][4];
            // threshold: max over waves of the wave's 5th-best key
            u64 tv = (lane < NW) ? s_wtop[lane][4] : 0ull;
            #pragma unroll
            for (int off = 1; off < 64; off <<= 1) {
                const u64 o = __shfl_xor(tv, off);
                tv = o > tv ? o : tv;
            }
            const u64 T = tv;
            int C = 0;
            while (C < MAXC) {
                u64 m = ck;
                #pragma unroll
                for (int off = 1; off < 64; off <<= 1) {
                    const u64 o = __shfl_xor(m, off);
                    m = o > m ? o : m;
                }
                if (m <= T) break;   // no candidate certainly above all outsiders
                const u64 bal = __ballot(ck == m);
                const int ln = (int)__ffsll(bal) - 1;
                if (lane == 0) { s_cln[C] = ln; s_csp[C] = (int)(m & 0x1FFFull) - 1; }
                if (ck == m) ck = 0ull;          // selected -> processed
                const int gw = ln >> 2, gr = ln & 3;
                const float jx1 = s_wgeom[gw][gr][0];
                const float jy1 = s_wgeom[gw][gr][1];
                const float jx2 = s_wgeom[gw][gr][2];
                const float jy2 = s_wgeom[gw][gr][3];
                const float ja  = s_wgeom[gw][gr][4];
                if (ck != 0ull) {                // decay my candidate (exact ops)
                    const float xx1 = fmaxf(jx1, cx1);
                    const float yy1 = fmaxf(jy1, cy1);
                    const float xx2 = fminf(jx2, cx2);
                    const float yy2 = fminf(jy2, cy2);
                    const float w = fmaxf(xx2 - xx1, 0.0f);
                    const float h = fmaxf(yy2 - yy1, 0.0f);
                    const float inter = w * h;
                    if (inter > 0.0f) {
                        const float iou = inter / (ja + car - inter);
                        float s = __uint_as_float((unsigned)(ck >> 25));
                        s *= __expf(iou * iou * -2.0f);
                        ck = ((u64)__float_as_uint(s) << 25) | (ck & 0x1FFFFFFull);
                    }
                }
                ++C;
            }
            if (lane == 0) s_C = C;
        }
        __syncthreads();

        // (3) all waves apply committed decays in commit order (bit-exact)
        const int C = s_C;
        remaining -= C;
        bool wdirty = false;
        for (int t = 0; t < C; ++t) {
            const int ln = s_cln[t];
            const int sp = s_csp[t];
            const int gw = ln >> 2, gr = ln & 3;
            const float jx1 = s_wgeom[gw][gr][0];
            const float jy1 = s_wgeom[gw][gr][1];
            const float jx2 = s_wgeom[gw][gr][2];
            const float jy2 = s_wgeom[gw][gr][3];
            const float ja  = s_wgeom[gw][gr][4];
            // wave-level skip: no geometric overlap => all weights exactly 1.0
            if (jx1 > wbx2 || jx2 < wbx1 || jy1 > wby2 || jy2 < wby1) continue;
            wdirty = true;
            #pragma unroll
            for (int k = 0; k < KPT; ++k) {
                if (tid * KPT + k == sp) {
                    fin[k] = cur[k];          // freeze at selection time
                    cur[k] = NEG_INF;         // mark processed
                } else {
                    const float xx1 = fmaxf(jx1, bx1[k]);
                    const float yy1 = fmaxf(jy1, by1[k]);
                    const float xx2 = fminf(jx2, bx2[k]);
                    const float yy2 = fminf(jy2, by2[k]);
                    const float w = fmaxf(xx2 - xx1, 0.0f);
                    const float h = fmaxf(yy2 - yy1, 0.0f);
                    const float inter = w * h;
                    const float iou = inter / (ja + bar[k] - inter);
                    cur[k] *= __expf(iou * iou * -2.0f);  // -inf stays -inf
                }
            }
        }
        rebuild = wdirty;
        __syncthreads();
    }

    // ---- scatter outputs back to original order ----
    #pragma unroll
    for (int k = 0; k < KPT; ++k) {
        const int oi = 4095 - (int)((klo[k] >> 13) & 0xFFFu);
        out[oi] = fin[k];
        out[N_BOX + oi] = (fin[k] > 0.05f) ? 1.0f : 0.0f;
    }
}

extern "C" void kernel_launch(void* const* d_in, const int* in_sizes, int n_in,
                              void* d_out, int out_size, void* d_ws, size_t ws_size,
                              hipStream_t stream) {
    const float* boxes  = (const float*)d_in[0];
    const float* scores = (const float*)d_in[1];
    float* out = (float*)d_out;
    soft_nms_kernel<<<1, NT, 0, stream>>>(boxes, scores, out);
}